// Round 21
// baseline (155.514 us; speedup 1.0000x reference)
//
#include <hip/hip_runtime.h>
#include <hip/hip_bf16.h>
#include <hip/hip_fp8.h>
#include <stdint.h>

#define NROW 8192
#define DIM  256
#define BK   64
#define MT   32
#define NT   128     // 8192 / BK

typedef float  f32x4  __attribute__((ext_vector_type(4)));
typedef __bf16 bf16x8 __attribute__((ext_vector_type(8)));
typedef unsigned short ushort8 __attribute__((ext_vector_type(8)));
typedef unsigned short ushort4s __attribute__((ext_vector_type(4)));

// round-to-nearest-even f32 -> bf16 (bit pattern)
__device__ __forceinline__ unsigned short f2bf(float f) {
  union { float f; uint32_t u; } v; v.f = f;
  uint32_t u = v.u;
  return (unsigned short)((u + 0x7FFFu + ((u >> 16) & 1u)) >> 16);
}
__device__ __forceinline__ unsigned char f2e4m3(float x) {
  return (unsigned char)__hip_cvt_float_to_fp8(x, __HIP_SATFINITE, __HIP_E4M3);
}

// ---------------- K0: d = rsqrt(rowsum(g)); g8 = e4m3(g) ----------------
// Block-per-row (best measured variant). g reads NON-TEMPORAL (zero reuse)
// -> keeps 64MB g8 L3-resident for K2.
__global__ __launch_bounds__(256) void k_rowsum_cast(const float* __restrict__ g,
                                                     float* __restrict__ d,
                                                     unsigned char* __restrict__ g8) {
  int r = blockIdx.x;
  const f32x4* row = (const f32x4*)(g + (size_t)r * NROW);
  unsigned char* grow = g8 + (size_t)r * NROW;
  float s = 0.f;
#pragma unroll
  for (int i = 0; i < 8; ++i) {
    int e4 = threadIdx.x + i * 256;
    f32x4 v = __builtin_nontemporal_load(row + e4);
    s += (v[0] + v[1]) + (v[2] + v[3]);
    uint32_t pk = (uint32_t)f2e4m3(v[0]) | ((uint32_t)f2e4m3(v[1]) << 8) |
                  ((uint32_t)f2e4m3(v[2]) << 16) | ((uint32_t)f2e4m3(v[3]) << 24);
    *(uint32_t*)(grow + e4 * 4) = pk;
  }
#pragma unroll
  for (int off = 32; off > 0; off >>= 1) s += __shfl_down(s, off, 64);
  __shared__ float red[4];
  int lane = threadIdx.x & 63, w = threadIdx.x >> 6;
  if (lane == 0) red[w] = s;
  __syncthreads();
  if (threadIdx.x == 0) {
    float t = (red[0] + red[1]) + (red[2] + red[3]);
    d[r] = rsqrtf(t);
  }
}

// ---------------- K1: X8[kb][n][kin] = e4m3(64*d_j*h[j][n]), plus Wbf ----------------
// chunk kb: 32 k-rows x 256 cols, col n owns 32B at n*32.
__global__ __launch_bounds__(256) void k_buildx(const float* __restrict__ h,
                                                const float* __restrict__ d,
                                                const float* __restrict__ Wm,
                                                unsigned char* __restrict__ X8,
                                                unsigned short* __restrict__ Wbf) {
  int bid = blockIdx.x;
  int tid = threadIdx.x;
  if (bid >= 256) {  // W cast: 32 blocks x 2048 elements
    int e0 = (bid - 256) * 2048 + tid * 8;
    float4 w0 = *(const float4*)(Wm + e0);
    float4 w1 = *(const float4*)(Wm + e0 + 4);
    ushort8 o;
    o[0] = f2bf(w0.x); o[1] = f2bf(w0.y); o[2] = f2bf(w0.z); o[3] = f2bf(w0.w);
    o[4] = f2bf(w1.x); o[5] = f2bf(w1.y); o[6] = f2bf(w1.z); o[7] = f2bf(w1.w);
    *(ushort8*)(Wbf + e0) = o;
    return;
  }
  int kb = bid;
  int j0 = kb * 32;
  __shared__ float tile[32][DIM];
  __shared__ float dl[32];   // holds 64*d
#pragma unroll
  for (int i = 0; i < 8; ++i) {
    int e = i * 256 + tid;
    int rr = e >> 6, c4 = e & 63;
    *(float4*)&tile[rr][c4 * 4] =
        *(const float4*)(h + (size_t)(j0 + rr) * DIM + c4 * 4);
  }
  if (tid < 32) dl[tid] = 64.f * d[j0 + tid];
  __syncthreads();
  unsigned char outv[32];
#pragma unroll
  for (int kin = 0; kin < 32; ++kin)
    outv[kin] = f2e4m3(tile[kin][tid] * dl[kin]);
  uint4* dst = (uint4*)(X8 + (size_t)kb * 8192 + tid * 32);
  const uint4* src = (const uint4*)outv;
  dst[0] = src[0]; dst[1] = src[1];
}

// ---------------- K2 (FUSED): out = relu((h + (d/64)*(g8@X8)) @ Wbf^T + b) ----------------
// KSPLIT=1, MT=32, 512 thr (8 waves 2Mx4N), grid 256 = 1 block/CU (8 waves/CU,
// same as R18 best). Full-K per block -> no zpart round-trip; K3 logic runs as
// an in-block epilogue. A LDS-staged (4 bufs x 2KB, one width-4 gload_lds per
// wave per stage -> R18's verified vmcnt 18/26 ladder unchanged at 9 ops/sub-iter).
// B in VGPRs (depth-2 ping-pong), 16B-piece XOR swizzle on A.
__global__ __launch_bounds__(512, 1) void k_gemm_fused(const unsigned char* __restrict__ g8,
                                                       const unsigned char* __restrict__ X8,
                                                       const float* __restrict__ h,
                                                       const float* __restrict__ d,
                                                       const unsigned short* __restrict__ Wbf,
                                                       const float* __restrict__ bias,
                                                       float* __restrict__ out) {
  int m0 = blockIdx.x * MT;

  __shared__ unsigned char A[4][MT][BK];        // 4 bufs x 2KB
  __shared__ unsigned short agg[MT][DIM + 8];   // 32 x 264 bf16 = 16.5KB

  int tid = threadIdx.x;
  int lane = tid & 63, w = tid >> 6;
  int wr = w >> 2, wc = w & 3;
  int frow = lane & 15, kgrp = lane >> 4;

  // A staging: wave w covers rows w*4..w*4+3 (256B region, 4B/lane).
  // lane l -> row w*4 + (l>>4), dest 4B at (l&15)*4; dest 16B piece
  // pd=(l&15)>>2, swizzled source piece ps = pd ^ ((row>>1)&3).
  int arow = w * 4 + (lane >> 4);
  int ps16 = ((lane & 15) >> 2) ^ ((arow >> 1) & 3);
  const unsigned char* asrc = g8 + (size_t)(m0 + arow) * NROW + ps16 * 16 + (lane & 3) * 4;
  // B: col = wc*64 + nf*16 + frow of chunk; lane k-piece kgrp*8 (8B)
  const unsigned char* xcol = X8 + (size_t)(wc * 64 + frow) * 32 + kgrp * 8;

  f32x4 acc[4];
#pragma unroll
  for (int j = 0; j < 4; ++j) acc[j] = (f32x4)0.f;

  auto stageA = [&](int t) {   // t wrapped to [0,NT); 1 width-4 gload per wave
    __builtin_amdgcn_global_load_lds(
        (const __attribute__((address_space(1))) uint32_t*)(asrc + (size_t)t * BK),
        (__attribute__((address_space(3))) uint32_t*)((char*)&A[0][0][0] + (t & 3) * 2048 + w * 256),
        4, 0, 0);
  };
  // bv[kk*4+nf], kk = chunk half (2t+kk), nf = col fragment
  auto loadB = [&](int t, long* bv) {
    const unsigned char* p = xcol + (size_t)(2 * t) * 8192;
#pragma unroll
    for (int kk = 0; kk < 2; ++kk)
#pragma unroll
      for (int nf = 0; nf < 4; ++nf)
        bv[kk * 4 + nf] = *(const long*)(p + kk * 8192 + nf * 512);
  };

  auto compute = [&](int buf, long* bv) {
    int row = wr * 16 + frow;
    int rb = buf * 2048 + row * 64;
    int sw = (row >> 1) & 3;
#pragma unroll
    for (int kk = 0; kk < 2; ++kk) {
      int p16 = kk * 2 + (kgrp >> 1);
      int off = rb + ((p16 ^ sw) << 4) + (kgrp & 1) * 8;
      long a = *(const long*)((const char*)&A[0][0][0] + off);
#pragma unroll
      for (int nf = 0; nf < 4; ++nf)
        acc[nf] = __builtin_amdgcn_mfma_f32_16x16x32_fp8_fp8(a, bv[kk * 4 + nf], acc[nf], 0, 0, 0);
    }
  };

  long b0[8], b1[8];
  stageA(0); stageA(1); stageA(2);   // 3 VMEM per wave
  loadB(0, b0); loadB(1, b1);        // +16 -> 19 outstanding
  asm volatile("s_waitcnt vmcnt(18)" ::: "memory");   // stageA(0) retired

  for (int t = 0; t < NT; t += 2) {
    asm volatile("s_waitcnt vmcnt(26)" ::: "memory");   // stageA(t) retired
    __builtin_amdgcn_s_barrier();
    stageA((t + 3) & (NT - 1));
    compute(t & 3, b0);
    loadB((t + 2) & (NT - 1), b0);
    asm volatile("s_waitcnt vmcnt(26)" ::: "memory");   // stageA(t+1) retired
    __builtin_amdgcn_s_barrier();
    stageA((t + 4) & (NT - 1));
    compute((t + 1) & 3, b1);
    loadB((t + 3) & (NT - 1), b1);
  }
  asm volatile("s_waitcnt vmcnt(0)" ::: "memory");

  // ---- fused epilogue: agg = bf16(h + (d/64)*z) into LDS ----
#pragma unroll
  for (int nf = 0; nf < 4; ++nf) {
    int col = wc * 64 + nf * 16 + frow;
#pragma unroll
    for (int r = 0; r < 4; ++r) {
      int row = wr * 16 + kgrp * 4 + r;
      float dr = d[m0 + row] * 0.015625f;
      float hv = h[(size_t)(m0 + row) * DIM + col];
      agg[row][col] = f2bf(hv + dr * acc[nf][r]);
    }
  }
  __syncthreads();

  // ---- K3 logic in-block: out = relu(agg @ Wbf^T + bias) ----
  f32x4 acc2[4];
#pragma unroll
  for (int j = 0; j < 4; ++j) acc2[j] = (f32x4)0.f;

#pragma unroll
  for (int t = 0; t < 8; ++t) {
    int k0 = t * 32;
    const ushort8* pa = (const ushort8*)&agg[wr * 16 + frow][k0 + kgrp * 8];
    bf16x8 af = __builtin_bit_cast(bf16x8, *pa);
#pragma unroll
    for (int nf = 0; nf < 4; ++nf) {
      int c = wc * 64 + nf * 16 + frow;
      const ushort8* pw = (const ushort8*)(Wbf + (size_t)c * DIM + k0 + kgrp * 8);
      bf16x8 bw = __builtin_bit_cast(bf16x8, *pw);
      acc2[nf] = __builtin_amdgcn_mfma_f32_16x16x32_bf16(af, bw, acc2[nf], 0, 0, 0);
    }
  }

#pragma unroll
  for (int nf = 0; nf < 4; ++nf) {
    int col = wc * 64 + nf * 16 + frow;
#pragma unroll
    for (int r = 0; r < 4; ++r) {
      int row = m0 + wr * 16 + kgrp * 4 + r;
      float v = acc2[nf][r] + bias[col];
      out[(size_t)row * DIM + col] = fmaxf(v, 0.f);
    }
  }
}

extern "C" void kernel_launch(void* const* d_in, const int* in_sizes, int n_in,
                              void* d_out, int out_size, void* d_ws, size_t ws_size,
                              hipStream_t stream) {
  const float* g    = (const float*)d_in[0];
  const float* h    = (const float*)d_in[1];
  const float* Wm   = (const float*)d_in[2];
  const float* bias = (const float*)d_in[3];
  float* out = (float*)d_out;

  char* ws = (char*)d_ws;
  float* dvec           = (float*)ws;                          // 32 KB
  unsigned char* X8     = (unsigned char*)(ws + (32 << 10));   // 2 MB fp8
  unsigned short* Wbf   = (unsigned short*)(ws + (4 << 20));   // 128 KB
  unsigned char* g8     = (unsigned char*)(ws + (16 << 20));   // 64 MB fp8 copy of g

  k_rowsum_cast<<<NROW, 256, 0, stream>>>(g, dvec, g8);
  k_buildx<<<256 + 32, 256, 0, stream>>>(h, dvec, Wm, X8, Wbf);
  k_gemm_fused<<<NROW / MT, 512, 0, stream>>>(g8, X8, h, dvec, Wbf, bias, out);
}

// Round 22
// 109.180 us; speedup vs baseline: 1.4244x; 1.4244x over previous
//
#include <hip/hip_runtime.h>
#include <hip/hip_bf16.h>
#include <hip/hip_fp8.h>
#include <stdint.h>

#define NROW 8192
#define DIM  256
#define BK   64
#define MT   64
#define KSPLIT 4
#define NT   32      // (8192/KSPLIT)/BK

typedef float  f32x4  __attribute__((ext_vector_type(4)));
typedef __bf16 bf16x8 __attribute__((ext_vector_type(8)));
typedef unsigned short ushort8 __attribute__((ext_vector_type(8)));
typedef unsigned short ushort4s __attribute__((ext_vector_type(4)));

// round-to-nearest-even f32 -> bf16 (bit pattern)
__device__ __forceinline__ unsigned short f2bf(float f) {
  union { float f; uint32_t u; } v; v.f = f;
  uint32_t u = v.u;
  return (unsigned short)((u + 0x7FFFu + ((u >> 16) & 1u)) >> 16);
}
__device__ __forceinline__ float bf2f(unsigned short us) {
  union { uint32_t u; float f; } t; t.u = (uint32_t)us << 16; return t.f;
}
__device__ __forceinline__ unsigned char f2e4m3(float x) {
  return (unsigned char)__hip_cvt_float_to_fp8(x, __HIP_SATFINITE, __HIP_E4M3);
}

__device__ __forceinline__ void gload_lds16(const void* gsrc, void* ldsdst) {
  __builtin_amdgcn_global_load_lds(
      (const __attribute__((address_space(1))) uint32_t*)gsrc,
      (__attribute__((address_space(3))) uint32_t*)ldsdst, 16, 0, 0);
}

// ---------------- K0: d = rsqrt(rowsum(g)); g8 = e4m3(g) ----------------
// Block-per-row (best measured variant). g reads NON-TEMPORAL (zero reuse)
// -> keeps 64MB g8 L3-resident for K2.
__global__ __launch_bounds__(256) void k_rowsum_cast(const float* __restrict__ g,
                                                     float* __restrict__ d,
                                                     unsigned char* __restrict__ g8) {
  int r = blockIdx.x;
  const f32x4* row = (const f32x4*)(g + (size_t)r * NROW);
  unsigned char* grow = g8 + (size_t)r * NROW;
  float s = 0.f;
#pragma unroll
  for (int i = 0; i < 8; ++i) {
    int e4 = threadIdx.x + i * 256;
    f32x4 v = __builtin_nontemporal_load(row + e4);
    s += (v[0] + v[1]) + (v[2] + v[3]);
    uint32_t pk = (uint32_t)f2e4m3(v[0]) | ((uint32_t)f2e4m3(v[1]) << 8) |
                  ((uint32_t)f2e4m3(v[2]) << 16) | ((uint32_t)f2e4m3(v[3]) << 24);
    *(uint32_t*)(grow + e4 * 4) = pk;
  }
#pragma unroll
  for (int off = 32; off > 0; off >>= 1) s += __shfl_down(s, off, 64);
  __shared__ float red[4];
  int lane = threadIdx.x & 63, w = threadIdx.x >> 6;
  if (lane == 0) red[w] = s;
  __syncthreads();
  if (threadIdx.x == 0) {
    float t = (red[0] + red[1]) + (red[2] + red[3]);
    d[r] = rsqrtf(t);
  }
}

// ---------------- K1: X8[kb][n][kin] = e4m3(64*d_j*h[j][n]), plus Wbf ----------------
// chunk kb: 32 k-rows x 256 cols, col n owns 32B at n*32.
__global__ __launch_bounds__(256) void k_buildx(const float* __restrict__ h,
                                                const float* __restrict__ d,
                                                const float* __restrict__ Wm,
                                                unsigned char* __restrict__ X8,
                                                unsigned short* __restrict__ Wbf) {
  int bid = blockIdx.x;
  int tid = threadIdx.x;
  if (bid >= 256) {  // W cast: 32 blocks x 2048 elements
    int e0 = (bid - 256) * 2048 + tid * 8;
    float4 w0 = *(const float4*)(Wm + e0);
    float4 w1 = *(const float4*)(Wm + e0 + 4);
    ushort8 o;
    o[0] = f2bf(w0.x); o[1] = f2bf(w0.y); o[2] = f2bf(w0.z); o[3] = f2bf(w0.w);
    o[4] = f2bf(w1.x); o[5] = f2bf(w1.y); o[6] = f2bf(w1.z); o[7] = f2bf(w1.w);
    *(ushort8*)(Wbf + e0) = o;
    return;
  }
  int kb = bid;
  int j0 = kb * 32;
  __shared__ float tile[32][DIM];
  __shared__ float dl[32];   // holds 64*d
#pragma unroll
  for (int i = 0; i < 8; ++i) {
    int e = i * 256 + tid;
    int rr = e >> 6, c4 = e & 63;
    *(float4*)&tile[rr][c4 * 4] =
        *(const float4*)(h + (size_t)(j0 + rr) * DIM + c4 * 4);
  }
  if (tid < 32) dl[tid] = 64.f * d[j0 + tid];
  __syncthreads();
  unsigned char outv[32];
#pragma unroll
  for (int kin = 0; kin < 32; ++kin)
    outv[kin] = f2e4m3(tile[kin][tid] * dl[kin]);
  uint4* dst = (uint4*)(X8 + (size_t)kb * 8192 + tid * 32);
  const uint4* src = (const uint4*)outv;
  dst[0] = src[0]; dst[1] = src[1];
}

// ---------------- K2: z_part[ks] = g8_tile @ X8 (fp8 MFMA, bf16 partials) ----------------
// R18 best config (105.4): shared-A LDS staging (4 bufs x 4KB, gload_lds,
// depth-3), counted vmcnt ladder (26 steady / 18 prologue), B in VGPRs
// (depth-2 ping-pong), 2 blocks/CU. zpart stores NON-TEMPORAL (write-once,
// read-once; keeps g8 L3-resident).
__global__ __launch_bounds__(256, 2) void k_gemm1(const unsigned char* __restrict__ g8,
                                                  const unsigned char* __restrict__ X8,
                                                  unsigned short* __restrict__ zpart) {
  int bid = blockIdx.x;
  int mtile = bid >> 2, ks = bid & 3;
  int m0 = mtile * MT;
  int kbase = ks * 2048;

  __shared__ unsigned char A[4][MT][BK];   // 4 bufs x 4KB

  int tid = threadIdx.x;
  int lane = tid & 63, w = tid >> 6;
  int frow = lane & 15, kgrp = lane >> 4;

  // staging: row = tid>>2, dest 16B piece tid&3 (linear dest);
  // source piece pre-swizzled: ps = (tid&3) ^ ((row>>1)&3)
  int ps = (tid & 3) ^ ((tid >> 3) & 3);
  const unsigned char* asrc = g8 + (size_t)(m0 + (tid >> 2)) * NROW + kbase + ps * 16;
  // B: col = w*64 + nf*16 + frow of chunk; lane k-piece kgrp*8 (8B)
  const unsigned char* xcol = X8 + (size_t)(ks * 64) * 8192 +
                              (size_t)(w * 64 + frow) * 32 + kgrp * 8;

  f32x4 acc[4][4];
#pragma unroll
  for (int i = 0; i < 4; ++i)
#pragma unroll
    for (int j = 0; j < 4; ++j) acc[i][j] = (f32x4)0.f;

  auto stageA = [&](int t) {   // t wrapped to [0,NT)
    gload_lds16(asrc + (size_t)t * BK, (char*)&A[0][0][0] + (t & 3) * 4096 + w * 1024);
  };
  // bv[kk*4+nf], kk = chunk half (2t+kk), nf = col fragment
  auto loadB = [&](int t, long* bv) {
    const unsigned char* p = xcol + (size_t)(2 * t) * 8192;
#pragma unroll
    for (int kk = 0; kk < 2; ++kk)
#pragma unroll
      for (int nf = 0; nf < 4; ++nf)
        bv[kk * 4 + nf] = *(const long*)(p + kk * 8192 + nf * 512);
  };

  auto compute = [&](int buf, long* bv) {
#pragma unroll
    for (int mf = 0; mf < 4; ++mf) {
      int row = mf * 16 + frow;
      int rb = buf * 4096 + row * 64;
      int sw = (row >> 1) & 3;
#pragma unroll
      for (int kk = 0; kk < 2; ++kk) {
        int p16 = kk * 2 + (kgrp >> 1);
        int off = rb + ((p16 ^ sw) << 4) + (kgrp & 1) * 8;
        long a = *(const long*)((const char*)&A[0][0][0] + off);
#pragma unroll
        for (int nf = 0; nf < 4; ++nf)
          acc[mf][nf] = __builtin_amdgcn_mfma_f32_16x16x32_fp8_fp8(
              a, bv[kk * 4 + nf], acc[mf][nf], 0, 0, 0);
      }
    }
  };

  long b0[8], b1[8];
  stageA(0); stageA(1); stageA(2);   // 3 VMEM
  loadB(0, b0); loadB(1, b1);        // +16 -> 19 outstanding
  asm volatile("s_waitcnt vmcnt(18)" ::: "memory");   // stageA(0) retired

  for (int t = 0; t < NT; t += 2) {
    asm volatile("s_waitcnt vmcnt(26)" ::: "memory");   // stageA(t) retired
    __builtin_amdgcn_s_barrier();
    stageA((t + 3) & (NT - 1));
    compute(t & 3, b0);
    loadB((t + 2) & (NT - 1), b0);
    asm volatile("s_waitcnt vmcnt(26)" ::: "memory");   // stageA(t+1) retired
    __builtin_amdgcn_s_barrier();
    stageA((t + 4) & (NT - 1));
    compute((t + 1) & 3, b1);
    loadB((t + 3) & (NT - 1), b1);
  }
  asm volatile("s_waitcnt vmcnt(0)" ::: "memory");

  // bf16 partial stores (z' = 64*z), non-temporal
  unsigned short* zp = zpart + (size_t)ks * NROW * DIM;
#pragma unroll
  for (int mf = 0; mf < 4; ++mf)
#pragma unroll
    for (int nf = 0; nf < 4; ++nf)
#pragma unroll
      for (int r = 0; r < 4; ++r) {
        int row = m0 + mf * 16 + kgrp * 4 + r;
        int col = w * 64 + nf * 16 + frow;
        __builtin_nontemporal_store(f2bf(acc[mf][nf][r]), &zp[(size_t)row * DIM + col]);
      }
}

// ---------------- K3: out = relu((h + (d/64)*Σz_part) @ Wbf^T + b) ----------------
__global__ __launch_bounds__(256) void k_out(float* __restrict__ out,
                                             const unsigned short* __restrict__ zpart,
                                             const float* __restrict__ h,
                                             const float* __restrict__ d,
                                             const unsigned short* __restrict__ Wbf,
                                             const float* __restrict__ bias) {
  int m0 = blockIdx.x * 32;
  __shared__ unsigned short agg[32][DIM + 8];
  int tid = threadIdx.x;
#pragma unroll
  for (int i = 0; i < 8; ++i) {
    int e = i * 256 + tid;
    int rr = e >> 6, c4 = e & 63;
    size_t off = (size_t)(m0 + rr) * DIM + c4 * 4;
    float zx = 0.f, zy = 0.f, zz = 0.f, zw = 0.f;
#pragma unroll
    for (int ks = 0; ks < KSPLIT; ++ks) {
      ushort4s zk = __builtin_nontemporal_load(
          (const ushort4s*)(zpart + (size_t)ks * NROW * DIM + off));
      zx += bf2f(zk[0]); zy += bf2f(zk[1]); zz += bf2f(zk[2]); zw += bf2f(zk[3]);
    }
    float4 hv = *(const float4*)(h + off);
    float dr = d[m0 + rr] * 0.015625f;   // un-scale the 64x in X
    agg[rr][c4 * 4 + 0] = f2bf(hv.x + dr * zx);
    agg[rr][c4 * 4 + 1] = f2bf(hv.y + dr * zy);
    agg[rr][c4 * 4 + 2] = f2bf(hv.z + dr * zz);
    agg[rr][c4 * 4 + 3] = f2bf(hv.w + dr * zw);
  }
  __syncthreads();

  int lane = tid & 63, w = tid >> 6;
  int frow = lane & 15, kgrp = lane >> 4;
  f32x4 acc[2][4];
#pragma unroll
  for (int i = 0; i < 2; ++i)
#pragma unroll
    for (int j = 0; j < 4; ++j) acc[i][j] = (f32x4)0.f;

#pragma unroll
  for (int t = 0; t < 8; ++t) {
    int k0 = t * 32;
    bf16x8 af[2];
#pragma unroll
    for (int mf = 0; mf < 2; ++mf) {
      const ushort8* p = (const ushort8*)&agg[mf * 16 + frow][k0 + kgrp * 8];
      af[mf] = __builtin_bit_cast(bf16x8, *p);
    }
#pragma unroll
    for (int nf = 0; nf < 4; ++nf) {
      int c = w * 64 + nf * 16 + frow;
      const ushort8* pw = (const ushort8*)(Wbf + (size_t)c * DIM + k0 + kgrp * 8);
      bf16x8 bfr = __builtin_bit_cast(bf16x8, *pw);
#pragma unroll
      for (int mf = 0; mf < 2; ++mf)
        acc[mf][nf] = __builtin_amdgcn_mfma_f32_16x16x32_bf16(af[mf], bfr, acc[mf][nf], 0, 0, 0);
    }
  }

#pragma unroll
  for (int mf = 0; mf < 2; ++mf)
#pragma unroll
    for (int nf = 0; nf < 4; ++nf)
#pragma unroll
      for (int r = 0; r < 4; ++r) {
        int row = m0 + mf * 16 + kgrp * 4 + r;
        int col = w * 64 + nf * 16 + frow;
        float v = acc[mf][nf][r] + bias[col];
        __builtin_nontemporal_store(fmaxf(v, 0.f), &out[(size_t)row * DIM + col]);
      }
}

extern "C" void kernel_launch(void* const* d_in, const int* in_sizes, int n_in,
                              void* d_out, int out_size, void* d_ws, size_t ws_size,
                              hipStream_t stream) {
  const float* g    = (const float*)d_in[0];
  const float* h    = (const float*)d_in[1];
  const float* Wm   = (const float*)d_in[2];
  const float* bias = (const float*)d_in[3];
  float* out = (float*)d_out;

  char* ws = (char*)d_ws;
  float* dvec           = (float*)ws;                          // 32 KB
  unsigned char* X8     = (unsigned char*)(ws + (32 << 10));   // 2 MB fp8
  unsigned short* Wbf   = (unsigned short*)(ws + (4 << 20));   // 128 KB
  unsigned char* g8     = (unsigned char*)(ws + (16 << 20));   // 64 MB fp8 copy of g
  unsigned short* zpart = (unsigned short*)(ws + (96ull << 20));  // 16 MB, 4 bf16 partials

  k_rowsum_cast<<<NROW, 256, 0, stream>>>(g, dvec, g8);
  k_buildx<<<256 + 32, 256, 0, stream>>>(h, dvec, Wm, X8, Wbf);
  k_gemm1<<<(NROW / MT) * KSPLIT, 256, 0, stream>>>(g8, X8, zpart);
  k_out<<<NROW / 32, 256, 0, stream>>>(out, zpart, h, dvec, Wbf, bias);
}

// Round 23
// 105.393 us; speedup vs baseline: 1.4756x; 1.0359x over previous
//
#include <hip/hip_runtime.h>
#include <hip/hip_bf16.h>
#include <hip/hip_fp8.h>
#include <stdint.h>

#define NROW 8192
#define DIM  256
#define BK   64
#define MT   64
#define KSPLIT 4
#define NT   32      // (8192/KSPLIT)/BK

typedef float  f32x4  __attribute__((ext_vector_type(4)));
typedef __bf16 bf16x8 __attribute__((ext_vector_type(8)));
typedef unsigned short ushort8 __attribute__((ext_vector_type(8)));
typedef unsigned short ushort4s __attribute__((ext_vector_type(4)));

// round-to-nearest-even f32 -> bf16 (bit pattern)
__device__ __forceinline__ unsigned short f2bf(float f) {
  union { float f; uint32_t u; } v; v.f = f;
  uint32_t u = v.u;
  return (unsigned short)((u + 0x7FFFu + ((u >> 16) & 1u)) >> 16);
}
__device__ __forceinline__ float bf2f(unsigned short us) {
  union { uint32_t u; float f; } t; t.u = (uint32_t)us << 16; return t.f;
}
__device__ __forceinline__ unsigned char f2e4m3(float x) {
  return (unsigned char)__hip_cvt_float_to_fp8(x, __HIP_SATFINITE, __HIP_E4M3);
}

__device__ __forceinline__ void gload_lds16(const void* gsrc, void* ldsdst) {
  __builtin_amdgcn_global_load_lds(
      (const __attribute__((address_space(1))) uint32_t*)gsrc,
      (__attribute__((address_space(3))) uint32_t*)ldsdst, 16, 0, 0);
}

// ---------------- K0: d = rsqrt(rowsum(g)); g8 = e4m3(g) ----------------
// Block-per-row (best measured variant). g reads NON-TEMPORAL (zero reuse)
// -> keeps 64MB g8 L3-resident for K2.
__global__ __launch_bounds__(256) void k_rowsum_cast(const float* __restrict__ g,
                                                     float* __restrict__ d,
                                                     unsigned char* __restrict__ g8) {
  int r = blockIdx.x;
  const f32x4* row = (const f32x4*)(g + (size_t)r * NROW);
  unsigned char* grow = g8 + (size_t)r * NROW;
  float s = 0.f;
#pragma unroll
  for (int i = 0; i < 8; ++i) {
    int e4 = threadIdx.x + i * 256;
    f32x4 v = __builtin_nontemporal_load(row + e4);
    s += (v[0] + v[1]) + (v[2] + v[3]);
    uint32_t pk = (uint32_t)f2e4m3(v[0]) | ((uint32_t)f2e4m3(v[1]) << 8) |
                  ((uint32_t)f2e4m3(v[2]) << 16) | ((uint32_t)f2e4m3(v[3]) << 24);
    *(uint32_t*)(grow + e4 * 4) = pk;
  }
#pragma unroll
  for (int off = 32; off > 0; off >>= 1) s += __shfl_down(s, off, 64);
  __shared__ float red[4];
  int lane = threadIdx.x & 63, w = threadIdx.x >> 6;
  if (lane == 0) red[w] = s;
  __syncthreads();
  if (threadIdx.x == 0) {
    float t = (red[0] + red[1]) + (red[2] + red[3]);
    d[r] = rsqrtf(t);
  }
}

// ---------------- K1: X8[kb][n][kin] = e4m3(64*d_j*h[j][n]), plus Wbf ----------------
// chunk kb: 32 k-rows x 256 cols, col n owns 32B at n*32.
__global__ __launch_bounds__(256) void k_buildx(const float* __restrict__ h,
                                                const float* __restrict__ d,
                                                const float* __restrict__ Wm,
                                                unsigned char* __restrict__ X8,
                                                unsigned short* __restrict__ Wbf) {
  int bid = blockIdx.x;
  int tid = threadIdx.x;
  if (bid >= 256) {  // W cast: 32 blocks x 2048 elements
    int e0 = (bid - 256) * 2048 + tid * 8;
    float4 w0 = *(const float4*)(Wm + e0);
    float4 w1 = *(const float4*)(Wm + e0 + 4);
    ushort8 o;
    o[0] = f2bf(w0.x); o[1] = f2bf(w0.y); o[2] = f2bf(w0.z); o[3] = f2bf(w0.w);
    o[4] = f2bf(w1.x); o[5] = f2bf(w1.y); o[6] = f2bf(w1.z); o[7] = f2bf(w1.w);
    *(ushort8*)(Wbf + e0) = o;
    return;
  }
  int kb = bid;
  int j0 = kb * 32;
  __shared__ float tile[32][DIM];
  __shared__ float dl[32];   // holds 64*d
#pragma unroll
  for (int i = 0; i < 8; ++i) {
    int e = i * 256 + tid;
    int rr = e >> 6, c4 = e & 63;
    *(float4*)&tile[rr][c4 * 4] =
        *(const float4*)(h + (size_t)(j0 + rr) * DIM + c4 * 4);
  }
  if (tid < 32) dl[tid] = 64.f * d[j0 + tid];
  __syncthreads();
  unsigned char outv[32];
#pragma unroll
  for (int kin = 0; kin < 32; ++kin)
    outv[kin] = f2e4m3(tile[kin][tid] * dl[kin]);
  uint4* dst = (uint4*)(X8 + (size_t)kb * 8192 + tid * 32);
  const uint4* src = (const uint4*)outv;
  dst[0] = src[0]; dst[1] = src[1];
}

// ---------------- K2: z_part[ks] = g8_tile @ X8 (fp8 MFMA, bf16 partials) ----------------
// R18 best config (105.4): shared-A LDS staging (4 bufs x 4KB, gload_lds,
// depth-3), counted vmcnt ladder (26 steady / 18 prologue), B in VGPRs
// (depth-2 ping-pong), 2 blocks/CU.
__global__ __launch_bounds__(256, 2) void k_gemm1(const unsigned char* __restrict__ g8,
                                                  const unsigned char* __restrict__ X8,
                                                  unsigned short* __restrict__ zpart) {
  int bid = blockIdx.x;
  int mtile = bid >> 2, ks = bid & 3;
  int m0 = mtile * MT;
  int kbase = ks * 2048;

  __shared__ unsigned char A[4][MT][BK];   // 4 bufs x 4KB

  int tid = threadIdx.x;
  int lane = tid & 63, w = tid >> 6;
  int frow = lane & 15, kgrp = lane >> 4;

  // staging: row = tid>>2, dest 16B piece tid&3 (linear dest);
  // source piece pre-swizzled: ps = (tid&3) ^ ((row>>1)&3)
  int ps = (tid & 3) ^ ((tid >> 3) & 3);
  const unsigned char* asrc = g8 + (size_t)(m0 + (tid >> 2)) * NROW + kbase + ps * 16;
  // B: col = w*64 + nf*16 + frow of chunk; lane k-piece kgrp*8 (8B)
  const unsigned char* xcol = X8 + (size_t)(ks * 64) * 8192 +
                              (size_t)(w * 64 + frow) * 32 + kgrp * 8;

  f32x4 acc[4][4];
#pragma unroll
  for (int i = 0; i < 4; ++i)
#pragma unroll
    for (int j = 0; j < 4; ++j) acc[i][j] = (f32x4)0.f;

  auto stageA = [&](int t) {   // t wrapped to [0,NT)
    gload_lds16(asrc + (size_t)t * BK, (char*)&A[0][0][0] + (t & 3) * 4096 + w * 1024);
  };
  // bv[kk*4+nf], kk = chunk half (2t+kk), nf = col fragment
  auto loadB = [&](int t, long* bv) {
    const unsigned char* p = xcol + (size_t)(2 * t) * 8192;
#pragma unroll
    for (int kk = 0; kk < 2; ++kk)
#pragma unroll
      for (int nf = 0; nf < 4; ++nf)
        bv[kk * 4 + nf] = *(const long*)(p + kk * 8192 + nf * 512);
  };

  auto compute = [&](int buf, long* bv) {
#pragma unroll
    for (int mf = 0; mf < 4; ++mf) {
      int row = mf * 16 + frow;
      int rb = buf * 4096 + row * 64;
      int sw = (row >> 1) & 3;
#pragma unroll
      for (int kk = 0; kk < 2; ++kk) {
        int p16 = kk * 2 + (kgrp >> 1);
        int off = rb + ((p16 ^ sw) << 4) + (kgrp & 1) * 8;
        long a = *(const long*)((const char*)&A[0][0][0] + off);
#pragma unroll
        for (int nf = 0; nf < 4; ++nf)
          acc[mf][nf] = __builtin_amdgcn_mfma_f32_16x16x32_fp8_fp8(
              a, bv[kk * 4 + nf], acc[mf][nf], 0, 0, 0);
      }
    }
  };

  long b0[8], b1[8];
  stageA(0); stageA(1); stageA(2);   // 3 VMEM
  loadB(0, b0); loadB(1, b1);        // +16 -> 19 outstanding
  asm volatile("s_waitcnt vmcnt(18)" ::: "memory");   // stageA(0) retired

  for (int t = 0; t < NT; t += 2) {
    asm volatile("s_waitcnt vmcnt(26)" ::: "memory");   // stageA(t) retired
    __builtin_amdgcn_s_barrier();
    stageA((t + 3) & (NT - 1));
    compute(t & 3, b0);
    loadB((t + 2) & (NT - 1), b0);
    asm volatile("s_waitcnt vmcnt(26)" ::: "memory");   // stageA(t+1) retired
    __builtin_amdgcn_s_barrier();
    stageA((t + 4) & (NT - 1));
    compute((t + 1) & 3, b1);
    loadB((t + 3) & (NT - 1), b1);
  }
  asm volatile("s_waitcnt vmcnt(0)" ::: "memory");

  // bf16 partial stores (z' = 64*z)
  unsigned short* zp = zpart + (size_t)ks * NROW * DIM;
#pragma unroll
  for (int mf = 0; mf < 4; ++mf)
#pragma unroll
    for (int nf = 0; nf < 4; ++nf)
#pragma unroll
      for (int r = 0; r < 4; ++r) {
        int row = m0 + mf * 16 + kgrp * 4 + r;
        int col = w * 64 + nf * 16 + frow;
        zp[(size_t)row * DIM + col] = f2bf(acc[mf][nf][r]);
      }
}

// ---------------- K3: out = relu((h + (d/64)*Σz_part) @ Wbf^T + b) ----------------
__global__ __launch_bounds__(256) void k_out(float* __restrict__ out,
                                             const unsigned short* __restrict__ zpart,
                                             const float* __restrict__ h,
                                             const float* __restrict__ d,
                                             const unsigned short* __restrict__ Wbf,
                                             const float* __restrict__ bias) {
  int m0 = blockIdx.x * 32;
  __shared__ unsigned short agg[32][DIM + 8];
  int tid = threadIdx.x;
#pragma unroll
  for (int i = 0; i < 8; ++i) {
    int e = i * 256 + tid;
    int rr = e >> 6, c4 = e & 63;
    size_t off = (size_t)(m0 + rr) * DIM + c4 * 4;
    float zx = 0.f, zy = 0.f, zz = 0.f, zw = 0.f;
#pragma unroll
    for (int ks = 0; ks < KSPLIT; ++ks) {
      ushort4s zk = *(const ushort4s*)(zpart + (size_t)ks * NROW * DIM + off);
      zx += bf2f(zk[0]); zy += bf2f(zk[1]); zz += bf2f(zk[2]); zw += bf2f(zk[3]);
    }
    float4 hv = *(const float4*)(h + off);
    float dr = d[m0 + rr] * 0.015625f;   // un-scale the 64x in X
    agg[rr][c4 * 4 + 0] = f2bf(hv.x + dr * zx);
    agg[rr][c4 * 4 + 1] = f2bf(hv.y + dr * zy);
    agg[rr][c4 * 4 + 2] = f2bf(hv.z + dr * zz);
    agg[rr][c4 * 4 + 3] = f2bf(hv.w + dr * zw);
  }
  __syncthreads();

  int lane = tid & 63, w = tid >> 6;
  int frow = lane & 15, kgrp = lane >> 4;
  f32x4 acc[2][4];
#pragma unroll
  for (int i = 0; i < 2; ++i)
#pragma unroll
    for (int j = 0; j < 4; ++j) acc[i][j] = (f32x4)0.f;

#pragma unroll
  for (int t = 0; t < 8; ++t) {
    int k0 = t * 32;
    bf16x8 af[2];
#pragma unroll
    for (int mf = 0; mf < 2; ++mf) {
      const ushort8* p = (const ushort8*)&agg[mf * 16 + frow][k0 + kgrp * 8];
      af[mf] = __builtin_bit_cast(bf16x8, *p);
    }
#pragma unroll
    for (int nf = 0; nf < 4; ++nf) {
      int c = w * 64 + nf * 16 + frow;
      const ushort8* pw = (const ushort8*)(Wbf + (size_t)c * DIM + k0 + kgrp * 8);
      bf16x8 bfr = __builtin_bit_cast(bf16x8, *pw);
#pragma unroll
      for (int mf = 0; mf < 2; ++mf)
        acc[mf][nf] = __builtin_amdgcn_mfma_f32_16x16x32_bf16(af[mf], bfr, acc[mf][nf], 0, 0, 0);
    }
  }

#pragma unroll
  for (int mf = 0; mf < 2; ++mf)
#pragma unroll
    for (int nf = 0; nf < 4; ++nf)
#pragma unroll
      for (int r = 0; r < 4; ++r) {
        int row = m0 + mf * 16 + kgrp * 4 + r;
        int col = w * 64 + nf * 16 + frow;
        float v = acc[mf][nf][r] + bias[col];
        out[(size_t)row * DIM + col] = fmaxf(v, 0.f);
      }
}

extern "C" void kernel_launch(void* const* d_in, const int* in_sizes, int n_in,
                              void* d_out, int out_size, void* d_ws, size_t ws_size,
                              hipStream_t stream) {
  const float* g    = (const float*)d_in[0];
  const float* h    = (const float*)d_in[1];
  const float* Wm   = (const float*)d_in[2];
  const float* bias = (const float*)d_in[3];
  float* out = (float*)d_out;

  char* ws = (char*)d_ws;
  float* dvec           = (float*)ws;                          // 32 KB
  unsigned char* X8     = (unsigned char*)(ws + (32 << 10));   // 2 MB fp8
  unsigned short* Wbf   = (unsigned short*)(ws + (4 << 20));   // 128 KB
  unsigned char* g8     = (unsigned char*)(ws + (16 << 20));   // 64 MB fp8 copy of g
  unsigned short* zpart = (unsigned short*)(ws + (96ull << 20));  // 16 MB, 4 bf16 partials

  k_rowsum_cast<<<NROW, 256, 0, stream>>>(g, dvec, g8);
  k_buildx<<<256 + 32, 256, 0, stream>>>(h, dvec, Wm, X8, Wbf);
  k_gemm1<<<(NROW / MT) * KSPLIT, 256, 0, stream>>>(g8, X8, zpart);
  k_out<<<NROW / 32, 256, 0, stream>>>(out, zpart, h, dvec, Wbf, bias);
}